// Round 1
// baseline (204.305 us; speedup 1.0000x reference)
//
#include <hip/hip_runtime.h>

#define N_RAYS    65536
#define N_SAMPLES 128

// One wave (64 lanes) per ray; each lane owns samples j0 = 2*lane, j1 = 2*lane+1.
// trans[j] telescopes to sig_j/sig_0, so weight[j] = max(sig_j - sig_{j+1}, 0)/sig_0
// (clip upper bound never binds since sig > 0); weight[0] = weight[127] = 0.
__global__ __launch_bounds__(256) void neus_render_kernel(
    const float* __restrict__ sdf,       // [R, S]
    const float* __restrict__ color,     // [R, S, 3]
    const float* __restrict__ z_vals,    // [R, S]
    const float* __restrict__ s_ptr,     // [1]
    const float* __restrict__ bg,        // [3]
    float* __restrict__ pixel_out,       // [R, 3]
    float* __restrict__ invdepth_out,    // [R]
    float* __restrict__ weight_out)      // [R, S]
{
    const int lane = threadIdx.x & 63;
    const int ray  = (blockIdx.x * blockDim.x + threadIdx.x) >> 6;
    if (ray >= N_RAYS) return;

    const float s = s_ptr[0];
    const int j0 = lane * 2;
    const size_t row = (size_t)ray * N_SAMPLES;

    // ---- sigmoid of the two owned samples (coalesced float2 load) ----
    const float2 sd = *(const float2*)(sdf + row + j0);
    const float sig0 = 1.0f / (1.0f + __expf(-sd.x * s));
    const float sig1 = 1.0f / (1.0f + __expf(-sd.y * s));

    // neighbor sample (j0 + 2) lives in lane+1; sample 0 in lane 0
    const float sig_next  = __shfl_down(sig0, 1);
    const float sig_first = __shfl(sig0, 0);
    const float inv0 = 1.0f / sig_first;

    // weights (telescoped transmittance; edge samples are exactly zero)
    const float w0 = (lane == 0)  ? 0.0f : fmaxf(sig0 - sig1, 0.0f) * inv0;
    const float w1 = (lane == 63) ? 0.0f : fmaxf(sig1 - sig_next, 0.0f) * inv0;

    // ---- store weights (coalesced float2) ----
    *(float2*)(weight_out + row + j0) = make_float2(w0, w1);

    // ---- inverse depth partial ----
    const float2 zz = *(const float2*)(z_vals + row + j0);
    float invd = w0 / zz.x + w1 / zz.y;

    // ---- color partials: 6 consecutive floats per lane (3x float2, 8B aligned) ----
    const float2* cb = (const float2*)(color + (row + j0) * 3);
    const float2 c01 = cb[0];   // c0.r, c0.g
    const float2 c23 = cb[1];   // c0.b, c1.r
    const float2 c45 = cb[2];   // c1.g, c1.b
    float pr = w0 * c01.x + w1 * c23.y;
    float pg = w0 * c01.y + w1 * c45.x;
    float pb = w0 * c23.x + w1 * c45.y;
    float wsum = w0 + w1;

    // ---- wave-wide butterfly reduction of 5 scalars ----
    #pragma unroll
    for (int m = 32; m >= 1; m >>= 1) {
        pr   += __shfl_xor(pr, m);
        pg   += __shfl_xor(pg, m);
        pb   += __shfl_xor(pb, m);
        invd += __shfl_xor(invd, m);
        wsum += __shfl_xor(wsum, m);
    }

    if (lane == 0) {
        const float resid = 1.0f - wsum;
        pixel_out[ray * 3 + 0] = pr + resid * bg[0];
        pixel_out[ray * 3 + 1] = pg + resid * bg[1];
        pixel_out[ray * 3 + 2] = pb + resid * bg[2];
        invdepth_out[ray] = invd;
    }
}

extern "C" void kernel_launch(void* const* d_in, const int* in_sizes, int n_in,
                              void* d_out, int out_size, void* d_ws, size_t ws_size,
                              hipStream_t stream) {
    const float* sdf   = (const float*)d_in[0];
    const float* color = (const float*)d_in[1];
    const float* z     = (const float*)d_in[2];
    const float* s     = (const float*)d_in[3];
    const float* bg    = (const float*)d_in[4];

    float* out       = (float*)d_out;
    float* pixel     = out;                                  // [R,3]  = 196608
    float* invdepth  = out + (size_t)N_RAYS * 3;             // [R]    = 65536
    float* weight    = out + (size_t)N_RAYS * 3 + N_RAYS;    // [R,S]  = 8388608

    // one wave per ray: 65536 waves -> 16384 blocks of 256 threads (4 rays/block)
    const int block = 256;
    const int grid  = (N_RAYS * 64) / block;
    neus_render_kernel<<<grid, block, 0, stream>>>(
        sdf, color, z, s, bg, pixel, invdepth, weight);
}